// Round 6
// baseline (30.908 us; speedup 1.0000x reference)
//
#include <hip/hip_runtime.h>
#include <math.h>

#define BB 4
#define TT 2048
#define DIM 256
#define MROWS (BB*TT)               // 8192
#define MN ((size_t)MROWS*DIM)      // 2097152 elements per tensor
#define NTOT 768
#define SCALE 0.0625f
#define HALF 16

typedef __attribute__((ext_vector_type(8))) short short8;
typedef __attribute__((ext_vector_type(4))) float f32x4;
typedef __attribute__((ext_vector_type(8))) unsigned short ushort8v;

__device__ __forceinline__ ushort f2bf(float f) {
    unsigned u = __builtin_bit_cast(unsigned, f);
    u += 0x7fffu + ((u >> 16) & 1u);
    return (ushort)(u >> 16);
}
__device__ __forceinline__ float bf2f(ushort u) {
    return __builtin_bit_cast(float, (unsigned)u << 16);
}
__device__ __forceinline__ ushort8v pack8(f32x4 lo, f32x4 hi) {
    ushort8v o;
    o[0] = f2bf(lo[0]); o[1] = f2bf(lo[1]); o[2] = f2bf(lo[2]); o[3] = f2bf(lo[3]);
    o[4] = f2bf(hi[0]); o[5] = f2bf(hi[1]); o[6] = f2bf(hi[2]); o[7] = f2bf(hi[3]);
    return o;
}

#define GLOAD16(g, l) __builtin_amdgcn_global_load_lds( \
    (const __attribute__((address_space(1))) void*)(g), \
    (__attribute__((address_space(3))) void*)(l), 16, 0, 0)

// ---------------- MFMA GEMM: qkv = bf16( x @ Wcat^T + bias ), + stat partials ----------------
// Reads x/W as fp32 directly; in-register f2bf; same swizzled LDS layout as before.
// BM=64, BN=128, BK=64; grid 128x6 = 768 blocks = 3/CU. Double-buffered 2-phase.
#define A_TILE (64*64)
#define B_TILE (128*64)
__global__ __launch_bounds__(256) void gemm_kernel(
    const float* __restrict__ x,
    const float* __restrict__ Wq, const float* __restrict__ Wk, const float* __restrict__ Wv,
    const float* __restrict__ bq, const float* __restrict__ bk, const float* __restrict__ bv,
    ushort* __restrict__ qkv, float* __restrict__ statacc)
{
    __shared__ ushort As[2 * A_TILE];
    __shared__ ushort Bs[2 * B_TILE];

    int tid = threadIdx.x;
    int lane = tid & 63, w = tid >> 6;
    int wr = w >> 1, wc = w & 1;

    // XCD-aware remap: 768 blocks, 8 XCDs, 96/XCD, contiguous A-panel per XCD.
    int orig = blockIdx.x + blockIdx.y * 128;
    int wg = (orig & 7) * 96 + (orig >> 3);
    int mb = wg / 6, nb = wg % 6;
    int m0 = mb * 64, n0 = nb * 128;

    // block-uniform tensor selection (tiles are 128-wide, tensors 256-aligned)
    int which = n0 >> 8;
    const float* Wm   = which == 0 ? Wq : (which == 1 ? Wk : Wv);
    const float* bias = which == 0 ? bq : (which == 1 ? bk : bv);
    int nw0 = n0 & 255;

    // staging geometry: wave w fills A rows [w*16,+16), B rows [w*32,+32); 8 rows/slot-group
    int srow = lane >> 3;                 // 0..7 (== row&7 for all our rows)
    int sc   = lane & 7;                  // LDS 16B slot within row (linear)
    int kof  = (sc ^ srow) << 3;          // swizzled source k-offset (elements)
    const float* aRow = x  + (size_t)(m0  + w * 16 + srow) * DIM + kof;
    const float* bRow = Wm + (size_t)(nw0 + w * 32 + srow) * DIM + kof;
    int aBase = (w * 16 + srow) * 64 + sc * 8;
    int bBase = (w * 32 + srow) * 64 + sc * 8;

    f32x4 acc[2][4] = {};
    f32x4 ra[2][2], rb[4][2];

    auto loadT = [&](int kt) {
        int ko = kt * 64;
        #pragma unroll
        for (int i = 0; i < 2; i++) {
            ra[i][0] = *(const f32x4*)(aRow + (size_t)i * 8 * DIM + ko);
            ra[i][1] = *(const f32x4*)(aRow + (size_t)i * 8 * DIM + ko + 4);
        }
        #pragma unroll
        for (int j = 0; j < 4; j++) {
            rb[j][0] = *(const f32x4*)(bRow + (size_t)j * 8 * DIM + ko);
            rb[j][1] = *(const f32x4*)(bRow + (size_t)j * 8 * DIM + ko + 4);
        }
    };
    auto commitT = [&](int buf) {
        ushort* Ab = &As[buf * A_TILE];
        ushort* Bb = &Bs[buf * B_TILE];
        #pragma unroll
        for (int i = 0; i < 2; i++)
            *(ushort8v*)(&Ab[aBase + i * 8 * 64]) = pack8(ra[i][0], ra[i][1]);
        #pragma unroll
        for (int j = 0; j < 4; j++)
            *(ushort8v*)(&Bb[bBase + j * 8 * 64]) = pack8(rb[j][0], rb[j][1]);
    };

    int fr = lane & 15, fp = lane >> 4, swz = lane & 7;

    loadT(0);
    commitT(0);
    __syncthreads();
    int cur = 0;
    #pragma unroll
    for (int kt = 0; kt < 4; kt++) {
        if (kt < 3) loadT(kt + 1);         // global loads in flight during MFMA
        const ushort* a_lds = &As[cur * A_TILE];
        const ushort* b_lds = &Bs[cur * B_TILE];
        #pragma unroll
        for (int ks = 0; ks < 2; ks++) {
            short8 af[2], bf[4];
            #pragma unroll
            for (int i = 0; i < 2; i++) {
                int row = wr * 32 + i * 16 + fr;
                int slot = ks * 4 + fp;
                af[i] = *(const short8*)(&a_lds[row * 64 + ((slot ^ swz) << 3)]);
            }
            #pragma unroll
            for (int j = 0; j < 4; j++) {
                int row = wc * 64 + j * 16 + fr;
                int slot = ks * 4 + fp;
                bf[j] = *(const short8*)(&b_lds[row * 64 + ((slot ^ swz) << 3)]);
            }
            #pragma unroll
            for (int i = 0; i < 2; i++)
                #pragma unroll
                for (int j = 0; j < 4; j++)
                    acc[i][j] = __builtin_amdgcn_mfma_f32_16x16x32_bf16(
                        af[i], bf[j], acc[i][j], 0, 0, 0);
        }
        if (kt < 3) commitT(cur ^ 1);      // convert + ds_write next buffer
        __syncthreads();
        cur ^= 1;
    }

    // epilogue: bias, round to bf16, store, per-column stat partials
    int b_idx = mb >> 5;                   // 32 m-blocks per batch
    #pragma unroll
    for (int j = 0; j < 4; j++) {
        int col = nw0 + wc * 64 + j * 16 + fr;    // 0..255 within tensor
        float bb = bias[col];
        float s1 = 0.f, s2 = 0.f;
        ushort* outbase = qkv + (size_t)which * MN + col;
        #pragma unroll
        for (int i = 0; i < 2; i++) {
            #pragma unroll
            for (int rr = 0; rr < 4; rr++) {
                int row = m0 + wr * 32 + i * 16 + fp * 4 + rr;
                float y = acc[i][j][rr] + bb;
                ushort ub = f2bf(y);
                outbase[(size_t)row * DIM] = ub;
                float yr = bf2f(ub);
                s1 += yr; s2 += yr * yr;
            }
        }
        s1 += __shfl_xor(s1, 16, 64); s1 += __shfl_xor(s1, 32, 64);
        s2 += __shfl_xor(s2, 16, 64); s2 += __shfl_xor(s2, 32, 64);
        if (fp == 0) {
            float* sa = statacc + ((size_t)(which * BB + b_idx)) * 512 + col;
            atomicAdd(sa, s1);
            atomicAdd(sa + 256, s2);
        }
    }
}

// ---------------- banded attention: raw K/V gload_lds, folded norms, atomic final ----------------
__global__ __launch_bounds__(256) void attn_kernel(const ushort* __restrict__ qkv,
                                                   const float* __restrict__ statacc,
                                                   float* __restrict__ out)
{
    int orig = blockIdx.x + blockIdx.y * 64;
    int wg = (orig & 7) * 32 + (orig >> 3);
    int tile = wg & 63, b = wg >> 6;
    int t0 = tile * 32;

    const ushort* qg = qkv;
    const ushort* kg = qkv + MN;
    const ushort* vg = qkv + 2 * MN;

    __shared__ ushort Qs[32 * 256];   // q * (rq*rk), bf16, swizzled slots
    __shared__ ushort Ks[64 * 256];   // RAW k, swizzled via pre-swizzled global src
    __shared__ ushort Vs[64 * 256];   // RAW v, linear
    __shared__ float Ps[32][65];
    __shared__ float csp[4][64];
    __shared__ float qsc[256], qsh[256], vsc[256], vsh[256];

    int tid = threadIdx.x;
    int lane = tid & 63, w = tid >> 6;

    // stats -> folded scales (k-mean and score shift dropped: softmax shift-invariant)
    {
        int h = tid;
        float s1q = statacc[(size_t)(0 * BB + b) * 512 + h];
        float s2q = statacc[(size_t)(0 * BB + b) * 512 + 256 + h];
        float s1k = statacc[(size_t)(1 * BB + b) * 512 + h];
        float s2k = statacc[(size_t)(1 * BB + b) * 512 + 256 + h];
        float s1v = statacc[(size_t)(2 * BB + b) * 512 + h];
        float s2v = statacc[(size_t)(2 * BB + b) * 512 + 256 + h];
        float mq = s1q * (1.f / 2048.f);
        float rq = 1.f / sqrtf(s2q * (1.f / 2048.f) - mq * mq + 1e-5f);
        float mk = s1k * (1.f / 2048.f);
        float rk = 1.f / sqrtf(s2k * (1.f / 2048.f) - mk * mk + 1e-5f);
        float mv = s1v * (1.f / 2048.f);
        float rv = 1.f / sqrtf(s2v * (1.f / 2048.f) - mv * mv + 1e-5f);
        float qs = rq * rk;
        qsc[h] = qs;  qsh[h] = -mq * qs;
        vsc[h] = rv;  vsh[h] = -mv * rv;
    }
    __syncthreads();

    // issue RAW K (swizzled via global-side pre-swizzle) + RAW V (linear), 16B direct-to-LDS
    {
        int r0 = lane >> 5;              // 0..1 row within pair
        int sp = lane & 31;              // LDS 16B slot within row
        #pragma unroll
        for (int i = 0; i < 8; i++) {
            int rowbase = (w * 8 + i) * 2;
            int r = rowbase + r0;
            int gt = t0 - HALF + r;
            int gtc = gt < 0 ? 0 : (gt > TT - 1 ? TT - 1 : gt);   // clamped rows get csum==0
            int s = sp ^ (r & 7);        // inverse swizzle on global source
            GLOAD16(kg + (size_t)(b * TT + gtc) * DIM + s * 8, &Ks[rowbase * 256]);
            GLOAD16(vg + (size_t)(b * TT + gtc) * DIM + sp * 8, &Vs[rowbase * 256]);
        }
    }

    // stage Q (32x256) scaled by rq*rk, shifted by -mq*rq*rk; overlaps K/V in flight
    #pragma unroll
    for (int i = 0; i < 4; i++) {
        int idx = tid + i * 256;
        int qr = idx >> 5, sp = idx & 31;
        int h0 = sp * 8;
        ushort8v raw = *(const ushort8v*)(qg + ((size_t)(b * TT + t0 + qr)) * DIM + h0);
        ushort8v o;
        #pragma unroll
        for (int e = 0; e < 8; e++)
            o[e] = f2bf(bf2f(raw[e]) * qsc[h0 + e] + qsh[h0 + e]);
        *(ushort8v*)(&Qs[qr * 256 + ((sp ^ (qr & 7)) << 3)]) = o;
    }
    __syncthreads();   // drains Q ds_writes + K/V gload_lds together

    // MFMA scores 32x64: wave w owns col-frag w; 2 row-frags
    f32x4 sacc[2] = {};
    int fr = lane & 15, fp = lane >> 4, swz = lane & 7;
    int brow = w * 16 + fr;
    #pragma unroll
    for (int ks = 0; ks < 8; ks++) {
        int slot = ks * 4 + fp;
        short8 bfr = *(const short8*)(&Ks[brow * 256 + ((slot ^ swz) << 3)]);
        #pragma unroll
        for (int rf = 0; rf < 2; rf++) {
            int arow = rf * 16 + fr;
            short8 af = *(const short8*)(&Qs[arow * 256 + ((slot ^ swz) << 3)]);
            sacc[rf] = __builtin_amdgcn_mfma_f32_16x16x32_bf16(af, bfr, sacc[rf], 0, 0, 0);
        }
    }
    #pragma unroll
    for (int rf = 0; rf < 2; rf++)
        #pragma unroll
        for (int rr = 0; rr < 4; rr++)
            Ps[rf * 16 + fp * 4 + rr][w * 16 + fr] = sacc[rf][rr];
    __syncthreads();

    // softmax: thread (r = tid>>3) owns cols c0..c0+7
    int r = tid >> 3, c0 = (tid & 7) * 8;
    float sv[8];
    float mx = -1e30f;
    #pragma unroll
    for (int j = 0; j < 8; j++) {
        int c = c0 + j;
        int gt = t0 - HALF + c;
        bool valid = (c >= r) && (c <= r + 32) && (gt >= 0) && (gt < TT);
        sv[j] = valid ? Ps[r][c] * SCALE : -1e30f;
        mx = fmaxf(mx, sv[j]);
    }
    #pragma unroll
    for (int d = 1; d < 8; d <<= 1) mx = fmaxf(mx, __shfl_xor(mx, d, 64));
    float sum = 0.f;
    #pragma unroll
    for (int j = 0; j < 8; j++) { sv[j] = __expf(sv[j] - mx); sum += sv[j]; }
    #pragma unroll
    for (int d = 1; d < 8; d <<= 1) sum += __shfl_xor(sum, d, 64);
    float inv = 1.0f / sum;
    #pragma unroll
    for (int j = 0; j < 8; j++) Ps[r][c0 + j] = sv[j] * inv;
    __syncthreads();

    // partial column sums of P, 256-thread parallel
    {
        int c = tid & 63, rq4 = tid >> 6;
        float s = 0.f;
        #pragma unroll
        for (int j = 0; j < 8; j++) s += Ps[rq4 * 8 + j][c];
        csp[rq4][c] = s;
    }
    __syncthreads();

    // weighted sum of RAW v rows from LDS; affine fix; atomic accumulate into out
    int h = tid;
    float o = 0.f;
    #pragma unroll 4
    for (int c = 0; c < 64; c++) {
        float cs = csp[0][c] + csp[1][c] + csp[2][c] + csp[3][c];
        o += cs * bf2f(Vs[c * 256 + h]);
    }
    o = vsc[h] * o + 32.f * vsh[h];
    atomicAdd(&out[(size_t)b * DIM + h], o * (1.0f / TT));
}

extern "C" void kernel_launch(void* const* d_in, const int* in_sizes, int n_in,
                              void* d_out, int out_size, void* d_ws, size_t ws_size,
                              hipStream_t stream) {
    const float* x  = (const float*)d_in[0];
    const float* Wq = (const float*)d_in[1];
    const float* bq = (const float*)d_in[2];
    const float* Wk = (const float*)d_in[3];
    const float* bk = (const float*)d_in[4];
    const float* Wv = (const float*)d_in[5];
    const float* bv = (const float*)d_in[6];
    float* out = (float*)d_out;

    ushort* qkv = (ushort*)d_ws;                       // 3*MN ushorts (12.6 MB)
    float* statacc = (float*)(qkv + 3 * MN);           // 6144 floats (atomic sums)

    // in-graph memset nodes: zero stat accumulators and output (replays re-zero)
    hipMemsetAsync(statacc, 0, 6144 * sizeof(float), stream);
    hipMemsetAsync(out, 0, (size_t)out_size * sizeof(float), stream);

    gemm_kernel<<<dim3(128, 6), 256, 0, stream>>>(x, Wq, Wk, Wv, bq, bk, bv, qkv, statacc);
    attn_kernel<<<dim3(64, 4), 256, 0, stream>>>(qkv, statacc, out);
}

// Round 7
// 29.321 us; speedup vs baseline: 1.0541x; 1.0541x over previous
//
#include <hip/hip_runtime.h>
#include <math.h>

#define BB 4
#define TT 2048
#define DIM 256
#define MROWS (BB*TT)               // 8192
#define MN ((size_t)MROWS*DIM)      // 2097152 elements per tensor
#define SCALE 0.0625f
#define HALF 16

typedef __attribute__((ext_vector_type(8))) short short8;
typedef __attribute__((ext_vector_type(4))) float f32x4;
typedef __attribute__((ext_vector_type(8))) unsigned short ushort8v;

__device__ __forceinline__ ushort f2bf(float f) {
    unsigned u = __builtin_bit_cast(unsigned, f);
    u += 0x7fffu + ((u >> 16) & 1u);
    return (ushort)(u >> 16);
}
__device__ __forceinline__ float bf2f(ushort u) {
    return __builtin_bit_cast(float, (unsigned)u << 16);
}
__device__ __forceinline__ ushort8v pack8(f32x4 lo, f32x4 hi) {
    ushort8v o;
    o[0] = f2bf(lo[0]); o[1] = f2bf(lo[1]); o[2] = f2bf(lo[2]); o[3] = f2bf(lo[3]);
    o[4] = f2bf(hi[0]); o[5] = f2bf(hi[1]); o[6] = f2bf(hi[2]); o[7] = f2bf(hi[3]);
    return o;
}

#define GLOAD16(g, l) __builtin_amdgcn_global_load_lds( \
    (const __attribute__((address_space(1))) void*)(g), \
    (__attribute__((address_space(3))) void*)(l), 16, 0, 0)

// part layout: idx = ((wb*2+sum)*256 + col)*32 + mb ; wb = which*4+b ; 196608 floats.
// Every slot written by exactly one gemm block -> overwrite semantics, no zeroing.

// ---------------- MFMA GEMM: qkv = bf16( x @ Wcat^T + bias ), + stat partials ----------------
// fp32-direct staging (in-register f2bf), BM=64, BN=128, BK=64; grid 128x6 = 768 = 3/CU.
#define A_TILE (64*64)
#define B_TILE (128*64)
__global__ __launch_bounds__(256) void gemm_kernel(
    const float* __restrict__ x,
    const float* __restrict__ Wq, const float* __restrict__ Wk, const float* __restrict__ Wv,
    const float* __restrict__ bq, const float* __restrict__ bk, const float* __restrict__ bv,
    ushort* __restrict__ qkv, float* __restrict__ part, float* __restrict__ out)
{
    __shared__ ushort As[2 * A_TILE];
    __shared__ ushort Bs[2 * B_TILE];
    __shared__ float sred[2][2][128];   // [s1|s2][wr][col_local]

    int tid = threadIdx.x;
    int lane = tid & 63, w = tid >> 6;
    int wr = w >> 1, wc = w & 1;

    int orig = blockIdx.x + blockIdx.y * 128;
    if (orig == 0) {
        #pragma unroll
        for (int i = 0; i < 4; i++) out[i * 256 + tid] = 0.f;   // race-free: attn is a later dispatch
    }

    // XCD-aware remap: 768 blocks, 8 XCDs, 96/XCD, contiguous A-panel per XCD.
    int wg = (orig & 7) * 96 + (orig >> 3);
    int mb = wg / 6, nb = wg % 6;
    int m0 = mb * 64, n0 = nb * 128;

    int which = n0 >> 8;
    const float* Wm   = which == 0 ? Wq : (which == 1 ? Wk : Wv);
    const float* bias = which == 0 ? bq : (which == 1 ? bk : bv);
    int nw0 = n0 & 255;

    int srow = lane >> 3;                 // 0..7
    int sc   = lane & 7;                  // linear 16B slot
    int kof  = (sc ^ srow) << 3;          // swizzled source k-offset
    const float* aRow = x  + (size_t)(m0  + w * 16 + srow) * DIM + kof;
    const float* bRow = Wm + (size_t)(nw0 + w * 32 + srow) * DIM + kof;
    int aBase = (w * 16 + srow) * 64 + sc * 8;
    int bBase = (w * 32 + srow) * 64 + sc * 8;

    f32x4 acc[2][4] = {};
    f32x4 ra[2][2], rb[4][2];

    auto loadT = [&](int kt) {
        int ko = kt * 64;
        #pragma unroll
        for (int i = 0; i < 2; i++) {
            ra[i][0] = *(const f32x4*)(aRow + (size_t)i * 8 * DIM + ko);
            ra[i][1] = *(const f32x4*)(aRow + (size_t)i * 8 * DIM + ko + 4);
        }
        #pragma unroll
        for (int j = 0; j < 4; j++) {
            rb[j][0] = *(const f32x4*)(bRow + (size_t)j * 8 * DIM + ko);
            rb[j][1] = *(const f32x4*)(bRow + (size_t)j * 8 * DIM + ko + 4);
        }
    };
    auto commitT = [&](int buf) {
        ushort* Ab = &As[buf * A_TILE];
        ushort* Bb = &Bs[buf * B_TILE];
        #pragma unroll
        for (int i = 0; i < 2; i++)
            *(ushort8v*)(&Ab[aBase + i * 8 * 64]) = pack8(ra[i][0], ra[i][1]);
        #pragma unroll
        for (int j = 0; j < 4; j++)
            *(ushort8v*)(&Bb[bBase + j * 8 * 64]) = pack8(rb[j][0], rb[j][1]);
    };

    int fr = lane & 15, fp = lane >> 4, swz = lane & 7;

    loadT(0);
    commitT(0);
    __syncthreads();
    int cur = 0;
    #pragma unroll
    for (int kt = 0; kt < 4; kt++) {
        if (kt < 3) loadT(kt + 1);
        const ushort* a_lds = &As[cur * A_TILE];
        const ushort* b_lds = &Bs[cur * B_TILE];
        #pragma unroll
        for (int ks = 0; ks < 2; ks++) {
            short8 af[2], bf[4];
            #pragma unroll
            for (int i = 0; i < 2; i++) {
                int row = wr * 32 + i * 16 + fr;
                int slot = ks * 4 + fp;
                af[i] = *(const short8*)(&a_lds[row * 64 + ((slot ^ swz) << 3)]);
            }
            #pragma unroll
            for (int j = 0; j < 4; j++) {
                int row = wc * 64 + j * 16 + fr;
                int slot = ks * 4 + fp;
                bf[j] = *(const short8*)(&b_lds[row * 64 + ((slot ^ swz) << 3)]);
            }
            #pragma unroll
            for (int i = 0; i < 2; i++)
                #pragma unroll
                for (int j = 0; j < 4; j++)
                    acc[i][j] = __builtin_amdgcn_mfma_f32_16x16x32_bf16(
                        af[i], bf[j], acc[i][j], 0, 0, 0);
        }
        if (kt < 3) commitT(cur ^ 1);
        __syncthreads();
        cur ^= 1;
    }

    // epilogue: bias, round, store qkv; column sums -> LDS -> non-overlapping partials
    int b_idx = mb >> 5;
    int mb_local = mb & 31;
    #pragma unroll
    for (int j = 0; j < 4; j++) {
        int col_local = wc * 64 + j * 16 + fr;
        int col = nw0 + col_local;
        float bb = bias[col];
        float s1 = 0.f, s2 = 0.f;
        ushort* outbase = qkv + (size_t)which * MN + col;
        #pragma unroll
        for (int i = 0; i < 2; i++) {
            #pragma unroll
            for (int rr = 0; rr < 4; rr++) {
                int row = m0 + wr * 32 + i * 16 + fp * 4 + rr;
                float y = acc[i][j][rr] + bb;
                ushort ub = f2bf(y);
                outbase[(size_t)row * DIM] = ub;
                float yr = bf2f(ub);
                s1 += yr; s2 += yr * yr;
            }
        }
        s1 += __shfl_xor(s1, 16, 64); s1 += __shfl_xor(s1, 32, 64);
        s2 += __shfl_xor(s2, 16, 64); s2 += __shfl_xor(s2, 32, 64);
        if (fp == 0) { sred[0][wr][col_local] = s1; sred[1][wr][col_local] = s2; }
    }
    __syncthreads();
    if (tid < 128) {
        float p1 = sred[0][0][tid] + sred[0][1][tid];
        float p2 = sred[1][0][tid] + sred[1][1][tid];
        int wb = which * 4 + b_idx;
        int tcol = nw0 + tid;
        part[((size_t)(wb * 2 + 0) * 256 + tcol) * 32 + mb_local] = p1;
        part[((size_t)(wb * 2 + 1) * 256 + tcol) * 32 + mb_local] = p2;
    }
}

// ---------------- banded attention: inline stat reduce, raw-K gload_lds, global-V PV ----------------
__global__ __launch_bounds__(256) void attn_kernel(const ushort* __restrict__ qkv,
                                                   const float* __restrict__ part,
                                                   float* __restrict__ out)
{
    int orig = blockIdx.x + blockIdx.y * 64;
    int wg = (orig & 7) * 32 + (orig >> 3);
    int tile = wg & 63, b = wg >> 6;
    int t0 = tile * 32;

    const ushort* qg = qkv;
    const ushort* kg = qkv + MN;
    const ushort* vg = qkv + 2 * MN;

    __shared__ ushort Qs[32 * 256];   // q*(rq*rk), bf16, swizzled slots
    __shared__ ushort Ks[64 * 256];   // RAW k, swizzled via pre-swizzled global src
    __shared__ float Ps[32][65];
    __shared__ float csp[4][64];
    __shared__ float qsc[256], qsh[256];

    int tid = threadIdx.x;
    int lane = tid & 63, w = tid >> 6;

    // (1) issue RAW K direct-to-LDS early (no stat dependency)
    {
        int r0 = lane >> 5;
        int sp = lane & 31;
        #pragma unroll
        for (int i = 0; i < 8; i++) {
            int rowbase = (w * 8 + i) * 2;
            int r = rowbase + r0;
            int gt = t0 - HALF + r;
            int gtc = gt < 0 ? 0 : (gt > TT - 1 ? TT - 1 : gt);   // clamped rows get csum==0
            int s = sp ^ (r & 7);
            GLOAD16(kg + (size_t)(b * TT + gtc) * DIM + s * 8, &Ks[rowbase * 256]);
        }
    }

    // (2) reduce stat partials (fixed order -> deterministic), h = tid
    float sums[3][2];
    #pragma unroll
    for (int wq = 0; wq < 3; wq++) {
        #pragma unroll
        for (int sm = 0; sm < 2; sm++) {
            const float* p = part + ((size_t)((wq * 4 + b) * 2 + sm) * 256 + tid) * 32;
            float a = 0.f;
            #pragma unroll
            for (int m4 = 0; m4 < 8; m4++) {
                f32x4 v = *(const f32x4*)(p + m4 * 4);
                a += (v[0] + v[1]) + (v[2] + v[3]);
            }
            sums[wq][sm] = a;
        }
    }
    float mq = sums[0][0] * (1.f / 2048.f);
    float rq = 1.f / sqrtf(sums[0][1] * (1.f / 2048.f) - mq * mq + 1e-5f);
    float mk = sums[1][0] * (1.f / 2048.f);
    float rk = 1.f / sqrtf(sums[1][1] * (1.f / 2048.f) - mk * mk + 1e-5f);
    float mv = sums[2][0] * (1.f / 2048.f);
    float rv = 1.f / sqrtf(sums[2][1] * (1.f / 2048.f) - mv * mv + 1e-5f);
    float qs = rq * rk;
    qsc[tid] = qs;  qsh[tid] = -mq * qs;
    float vscr = rv, vshr = -mv * rv;     // only thread h=tid needs these -> registers
    __syncthreads();

    // (3) stage Q (32x256) scaled; K gloads still in flight
    #pragma unroll
    for (int i = 0; i < 4; i++) {
        int idx = tid + i * 256;
        int qr = idx >> 5, sp = idx & 31;
        int h0 = sp * 8;
        ushort8v raw = *(const ushort8v*)(qg + ((size_t)(b * TT + t0 + qr)) * DIM + h0);
        ushort8v o;
        #pragma unroll
        for (int e = 0; e < 8; e++)
            o[e] = f2bf(bf2f(raw[e]) * qsc[h0 + e] + qsh[h0 + e]);
        *(ushort8v*)(&Qs[qr * 256 + ((sp ^ (qr & 7)) << 3)]) = o;
    }
    __syncthreads();   // drains Q ds_writes + K gload_lds

    // (4) MFMA scores 32x64
    f32x4 sacc[2] = {};
    int fr = lane & 15, fp = lane >> 4, swz = lane & 7;
    int brow = w * 16 + fr;
    #pragma unroll
    for (int ks = 0; ks < 8; ks++) {
        int slot = ks * 4 + fp;
        short8 bfr = *(const short8*)(&Ks[brow * 256 + ((slot ^ swz) << 3)]);
        #pragma unroll
        for (int rf = 0; rf < 2; rf++) {
            int arow = rf * 16 + fr;
            short8 af = *(const short8*)(&Qs[arow * 256 + ((slot ^ swz) << 3)]);
            sacc[rf] = __builtin_amdgcn_mfma_f32_16x16x32_bf16(af, bfr, sacc[rf], 0, 0, 0);
        }
    }
    #pragma unroll
    for (int rf = 0; rf < 2; rf++)
        #pragma unroll
        for (int rr = 0; rr < 4; rr++)
            Ps[rf * 16 + fp * 4 + rr][w * 16 + fr] = sacc[rf][rr];
    __syncthreads();

    // (5) softmax: thread (r = tid>>3) owns cols c0..c0+7
    int r = tid >> 3, c0 = (tid & 7) * 8;
    float sv[8];
    float mx = -1e30f;
    #pragma unroll
    for (int j = 0; j < 8; j++) {
        int c = c0 + j;
        int gt = t0 - HALF + c;
        bool valid = (c >= r) && (c <= r + 32) && (gt >= 0) && (gt < TT);
        sv[j] = valid ? Ps[r][c] * SCALE : -1e30f;
        mx = fmaxf(mx, sv[j]);
    }
    #pragma unroll
    for (int d = 1; d < 8; d <<= 1) mx = fmaxf(mx, __shfl_xor(mx, d, 64));
    float sum = 0.f;
    #pragma unroll
    for (int j = 0; j < 8; j++) { sv[j] = __expf(sv[j] - mx); sum += sv[j]; }
    #pragma unroll
    for (int d = 1; d < 8; d <<= 1) sum += __shfl_xor(sum, d, 64);
    float inv = 1.0f / sum;
    #pragma unroll
    for (int j = 0; j < 8; j++) Ps[r][c0 + j] = sv[j] * inv;
    __syncthreads();

    // (6) partial column sums of P
    {
        int c = tid & 63, rq4 = tid >> 6;
        float s = 0.f;
        #pragma unroll
        for (int j = 0; j < 8; j++) s += Ps[rq4 * 8 + j][c];
        csp[rq4][c] = s;
    }
    __syncthreads();

    // (7) PV: weighted sum of RAW v rows direct from global (L2-resident, coalesced/wave)
    int h = tid;
    const ushort* vrow = vg + (size_t)b * TT * DIM + h;
    float o = 0.f;
    #pragma unroll 8
    for (int c = 0; c < 64; c++) {
        float cs = csp[0][c] + csp[1][c] + csp[2][c] + csp[3][c];
        int gt = t0 - HALF + c;
        int gtc = gt < 0 ? 0 : (gt > TT - 1 ? TT - 1 : gt);
        o += cs * bf2f(vrow[(size_t)gtc * DIM]);
    }
    o = vscr * o + 32.f * vshr;
    atomicAdd(&out[(size_t)b * DIM + h], o * (1.0f / TT));
}

extern "C" void kernel_launch(void* const* d_in, const int* in_sizes, int n_in,
                              void* d_out, int out_size, void* d_ws, size_t ws_size,
                              hipStream_t stream) {
    const float* x  = (const float*)d_in[0];
    const float* Wq = (const float*)d_in[1];
    const float* bq = (const float*)d_in[2];
    const float* Wk = (const float*)d_in[3];
    const float* bk = (const float*)d_in[4];
    const float* Wv = (const float*)d_in[5];
    const float* bv = (const float*)d_in[6];
    float* out = (float*)d_out;

    ushort* qkv = (ushort*)d_ws;                 // 3*MN ushorts (12.6 MB)
    float* part = (float*)(qkv + 3 * MN);        // 196608 floats (786 KB), overwrite-only

    gemm_kernel<<<dim3(128, 6), 256, 0, stream>>>(x, Wq, Wk, Wv, bq, bk, bv, qkv, part, out);
    attn_kernel<<<dim3(64, 4), 256, 0, stream>>>(qkv, part, out);
}